// Round 3
// baseline (82.602 us; speedup 1.0000x reference)
//
#include <hip/hip_runtime.h>
#include <hip/hip_bf16.h>

typedef __bf16 bf16x8 __attribute__((ext_vector_type(8)));
typedef float  f32x4  __attribute__((ext_vector_type(4)));

#define UBV    35.0f
#define SUMC   150.0f
#define SLOPE  0.2f
#define H1S    424      // s_h1 bf16 stride (848B = 212 dw ≡ 20 mod 32 → 2-way max)

__device__ __forceinline__ float lrelu(float x) { return x > 0.f ? x : SLOPE * x; }

// Fragment-ordered weight prep.
// w1f: 25 tiles × 64 lanes × 8 bf16   (tile nt: n = nt*16+c16, k = g*8+j, k>=17 -> 0)
// w2f: 4 quarters × 65 frags × 64 lanes × 8 bf16
//      frag (q,nt,kt): n = q*80+nt*16+c16, k = kt*32+g*8+j  (n>=300 or k>=400 -> 0)
__global__ void prep_kernel(const float* __restrict__ W1, const float* __restrict__ W2,
                            __bf16* __restrict__ w1f, __bf16* __restrict__ w2f)
{
    int idx = blockIdx.x * blockDim.x + threadIdx.x;   // octet index
    if (idx < 1600) {
        int t = idx >> 6, lane = idx & 63;
        int c16 = lane & 15, g = lane >> 4;
        int n = t * 16 + c16, k0 = g * 8;
        bf16x8 v;
        #pragma unroll
        for (int j = 0; j < 8; ++j)
            v[j] = (__bf16)((k0 + j < 17) ? W1[n * 17 + k0 + j] : 0.f);
        *(bf16x8*)(w1f + idx * 8) = v;
    } else if (idx < 1600 + 16640) {
        int i2 = idx - 1600;
        int f = i2 >> 6, lane = i2 & 63;
        int q = f / 65, rem = f - q * 65;
        int nt = rem / 13, kt = rem - nt * 13;
        int c16 = lane & 15, g = lane >> 4;
        int n = q * 80 + nt * 16 + c16;
        int k0 = kt * 32 + g * 8;
        bf16x8 v;
        #pragma unroll
        for (int j = 0; j < 8; ++j)
            v[j] = (__bf16)((n < 300 && k0 + j < 400) ? W2[n * 400 + k0 + j] : 0.f);
        *(bf16x8*)(w2f + i2 * 8) = v;
    }
}

// One block per CU. 4 waves; wave q holds the (q*80..q*80+80) N-quarter of W2
// in 260 VGPRs as MFMA B-fragments. Block processes 256 batch rows in 4 groups
// of 64; h1 round-trips through LDS (k-split producer -> n-split consumer).
__global__ __launch_bounds__(256, 1)
void actor_kernel(const float* __restrict__ state,
                  const __bf16* __restrict__ w1f,
                  const float* __restrict__ b1,
                  const __bf16* __restrict__ w2f,
                  const float* __restrict__ b2,
                  const float* __restrict__ W3,
                  const float* __restrict__ b3,
                  float* __restrict__ out)
{
    __shared__ __bf16 s_h1[64][H1S];       // 54,272B
    __shared__ float  s_state[64][36];     // 9,216B  (144B stride ≡ 4 mod 32 dw)
    __shared__ float  s_part[4][5][64];    // 5,120B

    const int tid  = threadIdx.x;
    const int q    = tid >> 6;             // wave = N-quarter
    const int ln   = tid & 63;
    const int g    = ln >> 4, c16 = ln & 15;
    const int brow = blockIdx.x * 256;

    // ---- resident B2 fragments: 65 coalesced 16B loads per lane ----
    bf16x8 B2f[5][13];
    {
        const __bf16* wq = w2f + q * (65 * 512);
        #pragma unroll
        for (int nt = 0; nt < 5; ++nt)
            #pragma unroll
            for (int kt = 0; kt < 13; ++kt)
                B2f[nt][kt] = *(const bf16x8*)(wq + (nt * 13 + kt) * 512 + ln * 8);
    }

    // ---- hoisted fold constants (L2-resident scalars) ----
    float w3r[5][5], b2r[5], b3r[5];
    #pragma unroll
    for (int nt = 0; nt < 5; ++nt) {
        int cc = q * 80 + nt * 16 + c16;
        b2r[nt] = (cc < 300) ? b2[cc] : 0.f;
        #pragma unroll
        for (int o = 0; o < 5; ++o)
            w3r[o][nt] = (cc < 300) ? W3[o * 300 + cc] : 0.f;
    }
    #pragma unroll
    for (int o = 0; o < 5; ++o) b3r[o] = b3[o];

    // zero h1 pad cols 400..415 once (never rewritten)
    for (int i = tid; i < 64 * 16; i += 256) {
        int r = i >> 4, c = 400 + (i & 15);
        s_h1[r][c] = (__bf16)0.f;
    }

    const int base1 = (q == 0) ? 0 : (q == 1) ? 7 : (q == 2) ? 13 : 19;
    const int cnt1  = (q == 0) ? 7 : 6;

    #pragma unroll 1
    for (int grp = 0; grp < 4; ++grp) {
        const int gbase = brow + grp * 64;

        // ---- stage state rows (zero-pad cols 17..35) ----
        for (int i = tid; i < 64 * 36; i += 256) {
            int r = i / 36, c = i - r * 36;
            s_state[r][c] = (c < 17) ? state[(gbase + r) * 17 + c] : 0.f;
        }
        __syncthreads();

        // ---- Phase A: layer 1, B1 frags per-group (regs freed for phase B) ----
        {
            bf16x8 B1f[7]; float b1r[7];
            #pragma unroll
            for (int t = 0; t < 7; ++t)
                if (t < cnt1) {
                    B1f[t] = *(const bf16x8*)(w1f + (base1 + t) * 512 + ln * 8);
                    b1r[t] = b1[(base1 + t) * 16 + c16];
                }
            #pragma unroll
            for (int mt = 0; mt < 4; ++mt) {
                const float* sp = &s_state[mt * 16 + c16][g * 8];
                f32x4 lo = *(const f32x4*)(sp);
                f32x4 hi = *(const f32x4*)(sp + 4);
                bf16x8 a;
                #pragma unroll
                for (int j = 0; j < 4; ++j) { a[j] = (__bf16)lo[j]; a[j + 4] = (__bf16)hi[j]; }
                #pragma unroll
                for (int t = 0; t < 7; ++t)
                    if (t < cnt1) {
                        f32x4 acc = {0.f, 0.f, 0.f, 0.f};
                        acc = __builtin_amdgcn_mfma_f32_16x16x32_bf16(a, B1f[t], acc, 0, 0, 0);
                        int jc = (base1 + t) * 16 + c16;
                        #pragma unroll
                        for (int r = 0; r < 4; ++r)
                            s_h1[mt * 16 + g * 4 + r][jc] = (__bf16)lrelu(acc[r] + b1r[t]);
                    }
            }
        }
        __syncthreads();

        // ---- Phase B: layer 2 MFMA (register B2) + fused layer-3 fold ----
        #pragma unroll 1
        for (int mt = 0; mt < 4; ++mt) {
            bf16x8 af[13];
            const __bf16* hp = &s_h1[mt * 16 + c16][0];
            #pragma unroll
            for (int kt = 0; kt < 13; ++kt)
                af[kt] = *(const bf16x8*)(hp + kt * 32 + g * 8);

            f32x4 acc[5];
            #pragma unroll
            for (int nt = 0; nt < 5; ++nt) acc[nt] = (f32x4){0.f, 0.f, 0.f, 0.f};
            #pragma unroll
            for (int kt = 0; kt < 13; ++kt)
                #pragma unroll
                for (int nt = 0; nt < 5; ++nt)
                    acc[nt] = __builtin_amdgcn_mfma_f32_16x16x32_bf16(af[kt], B2f[nt][kt], acc[nt], 0, 0, 0);

            float part[5][4];
            #pragma unroll
            for (int o = 0; o < 5; ++o)
                #pragma unroll
                for (int r = 0; r < 4; ++r) part[o][r] = 0.f;
            #pragma unroll
            for (int nt = 0; nt < 5; ++nt)
                #pragma unroll
                for (int r = 0; r < 4; ++r) {
                    float h2 = lrelu(acc[nt][r] + b2r[nt]);
                    #pragma unroll
                    for (int o = 0; o < 5; ++o) part[o][r] += h2 * w3r[o][nt];
                }

            #pragma unroll
            for (int o = 0; o < 5; ++o)
                #pragma unroll
                for (int r = 0; r < 4; ++r) {
                    float x = part[o][r];
                    x += __shfl_xor(x, 1);
                    x += __shfl_xor(x, 2);
                    x += __shfl_xor(x, 4);
                    x += __shfl_xor(x, 8);
                    part[o][r] = x;
                }
            #pragma unroll
            for (int o = 0; o < 5; ++o)
                if (c16 == o)
                    #pragma unroll
                    for (int r = 0; r < 4; ++r)
                        s_part[q][o][mt * 16 + g * 4 + r] = part[o][r];
        }
        __syncthreads();

        // ---- Epilogue: 16 lanes/wave -> 64 rows: sum quarters, QP, store ----
        if (ln < 16) {
            int rowl = q * 16 + ln;
            float v[5];
            #pragma unroll
            for (int o = 0; o < 5; ++o) {
                float s = s_part[0][o][rowl] + s_part[1][o][rowl]
                        + s_part[2][o][rowl] + s_part[3][o][rowl];
                v[o] = -lrelu(s + b3r[o]);
            }
            float bp[10];
            #pragma unroll
            for (int i = 0; i < 5; ++i) { bp[i] = v[i]; bp[i + 5] = v[i] - UBV; }
            float blo = -1e30f, glo = 0.f;
            #pragma unroll
            for (int j = 0; j < 10; ++j) {
                float b = bp[j];
                float gsum = 0.f;
                #pragma unroll
                for (int i = 0; i < 5; ++i) {
                    float z = v[i] - b;
                    z = fminf(fmaxf(z, 0.f), UBV);
                    gsum += z;
                }
                if (gsum >= SUMC && b > blo) { blo = b; glo = gsum; }
            }
            float bhi = 1e30f;
            #pragma unroll
            for (int j = 0; j < 10; ++j) {
                float b = bp[j];
                if (b > blo && b < bhi) bhi = b;
            }
            float mid = 0.5f * (blo + bhi);
            int nfree = 0;
            #pragma unroll
            for (int i = 0; i < 5; ++i)
                nfree += (v[i] > mid && v[i] < mid + UBV) ? 1 : 0;
            float nu = (nfree > 0) ? blo + (glo - SUMC) / (float)nfree : blo;

            int row = gbase + rowl;
            #pragma unroll
            for (int o = 0; o < 5; ++o) {
                float z = v[o] - nu;
                z = fminf(fmaxf(z, 0.f), UBV);
                out[row * 5 + o] = z;
            }
        }
        __syncthreads();
    }
}

extern "C" void kernel_launch(void* const* d_in, const int* in_sizes, int n_in,
                              void* d_out, int out_size, void* d_ws, size_t ws_size,
                              hipStream_t stream) {
    const float* state = (const float*)d_in[0];
    const float* W1    = (const float*)d_in[1];
    const float* b1    = (const float*)d_in[2];
    const float* W2    = (const float*)d_in[3];
    const float* b2    = (const float*)d_in[4];
    const float* W3    = (const float*)d_in[5];
    const float* b3    = (const float*)d_in[6];
    float* out = (float*)d_out;

    __bf16* w1f = (__bf16*)d_ws;           // 25*512  bf16 = 25,600B
    __bf16* w2f = w1f + 25 * 512;          // 260*512 bf16 = 266,240B

    const int octets = 1600 + 16640;       // 18,240 -> 72 blocks
    prep_kernel<<<(octets + 255) / 256, 256, 0, stream>>>(W1, W2, w1f, w2f);

    actor_kernel<<<256, 256, 0, stream>>>(state, w1f, b1, w2f, b2, W3, b3, out);
}

// Round 4
// 36.005 us; speedup vs baseline: 2.2942x; 2.2942x over previous
//
#include <hip/hip_runtime.h>
#include <hip/hip_bf16.h>

typedef __bf16 bf16x8 __attribute__((ext_vector_type(8)));
typedef float  f32x4  __attribute__((ext_vector_type(4)));

#define UBV   35.0f
#define SUMC  150.0f

__device__ __forceinline__ float lrelu(float x) { return fmaxf(x, 0.2f * x); }

// pack 2 f32 -> 2 fp8(e4m3) in low 16 bits
__device__ __forceinline__ unsigned pk8(float a, float b) {
    return ((unsigned)__builtin_amdgcn_cvt_pk_fp8_f32(a, b, 0, false)) & 0xffffu;
}
__device__ __forceinline__ long mk64(unsigned lo, unsigned hi) {
    return (long)(((unsigned long long)hi << 32) | (unsigned long long)lo);
}

// ---------------------------------------------------------------------------
// sigma mapping (phase A -> phase B handoff):
//   h1 k-slot kappa = kt*32 + g*8 + 4h + r   <->  acc tile nt=2kt+h, row rho=g*4+r
// So W1p tile nt, row rho holds weights of slot kappa; the phase-A accumulator
// pair (2kt,2kt+1) packs directly into the phase-B B-frag for kt. Same trick
// for phase B -> C with kappa2 over each wave's 80 n2-slots (K=96 padded).
// Biases: state k=17 := 1.0 carries b1; h1 slot 400 := 1.0 carries b2;
// z local-slot 79 (==1.0 via b2col) carries b3/4 per quarter.
// ---------------------------------------------------------------------------

__global__ void prep_kernel(const float* __restrict__ W1, const float* __restrict__ b1,
                            const float* __restrict__ W2, const float* __restrict__ b2,
                            const float* __restrict__ W3, const float* __restrict__ b3,
                            __bf16* __restrict__ w1p, uint2* __restrict__ w2p,
                            uint2* __restrict__ w3c)
{
    int idx = blockIdx.x * blockDim.x + threadIdx.x;
    if (idx < 1664) {
        // W1p: 26 bf16 A-frag tiles [nt][lane][8]; lane: row=c16, k=g*8+j
        int lane = idx & 63;
        int nt = idx >> 6;
        int c16 = lane & 15, g = lane >> 4;
        int kk = nt >> 1, hh = nt & 1;
        int kap = kk * 32 + (c16 >> 2) * 8 + hh * 4 + (c16 & 3);  // slot this row feeds
        bf16x8 v;
        #pragma unroll
        for (int j = 0; j < 8; ++j) {
            int k = g * 8 + j;
            float x = 0.f;
            if (kap < 400) {
                if (k < 17) x = W1[kap * 17 + k];
                else if (k == 17) x = b1[kap];
            } else if (kap == 400) {
                if (k == 17) x = 1.0f;     // bias-carrier slot: h1[400] = 1.0
            }
            v[j] = (__bf16)x;
        }
        *(bf16x8*)(w1p + idx * 8) = v;
    } else if (idx < 1664 + 16640) {
        // W2p: fp8 A-frags, 4 quarters x 5 tiles x 13 kt; lane: row=c16, k=g*8+j
        int i2 = idx - 1664;
        int fg = i2 >> 6, lane = i2 & 63;
        int q = fg / 65, rem = fg % 65;
        int t = rem / 13, kt = rem % 13;
        int c16 = lane & 15, g = lane >> 4;
        int local = t * 16 + c16;          // n2-slot within quarter [0,80)
        int ff = q * 79 + local;           // real n2 feature
        float v[8];
        #pragma unroll
        for (int j = 0; j < 8; ++j) {
            int kap = kt * 32 + g * 8 + j; // h1 slot
            float x = 0.f;
            if (local == 79) {
                x = (kap == 400) ? 1.0f : 0.f;          // h2 := b2col*1 = 1.0 row
            } else if (local < 79 && ff < 300) {
                if (kap < 400) x = W2[ff * 400 + kap];
                else if (kap == 400) x = b2[ff];
            }
            v[j] = x;
        }
        uint2 d;
        d.x = pk8(v[0], v[1]) | (pk8(v[2], v[3]) << 16);
        d.y = pk8(v[4], v[5]) | (pk8(v[6], v[7]) << 16);
        w2p[i2] = d;
    } else if (idx < 1664 + 16640 + 768) {
        // w3c: fp8 A-frags, 4 quarters x 3 k2 (K=96); lane: row=o(c16), k=g*8+j
        int i3 = idx - 1664 - 16640;
        int fg = i3 >> 6, lane = i3 & 63;
        int q = fg / 3, k2 = fg % 3;
        int o = lane & 15, g = lane >> 4;
        float v[8];
        #pragma unroll
        for (int j = 0; j < 8; ++j) {
            int t2  = 2 * k2 + (j >> 2);       // z-slot decode (sigma2)
            int rho = g * 4 + (j & 3);
            int local = t2 * 16 + rho;
            float x = 0.f;
            if (o < 5 && t2 < 5) {
                if (local == 79) x = b3[o] * 0.25f;
                else if (local < 79 && q * 79 + local < 300)
                    x = W3[o * 300 + q * 79 + local];
            }
            v[j] = x;
        }
        uint2 d;
        d.x = pk8(v[0], v[1]) | (pk8(v[2], v[3]) << 16);
        d.y = pk8(v[4], v[5]) | (pk8(v[6], v[7]) << 16);
        w3c[i3] = d;
    }
}

// ---------------------------------------------------------------------------
// Actor: 256 blocks x 512 threads. Waves 4-7 produce h1 frags (phase A),
// waves 0-3 hold a W2 N-quarter in fp8 VGPRs and consume (phases B+C).
// Block = 256 rows, 4 rounds x 4 m-tiles, h1 double-buffered, 9 barriers.
// ---------------------------------------------------------------------------
__global__ __launch_bounds__(512, 1)
void actor_kernel(const float* __restrict__ state,
                  const __bf16* __restrict__ w1p,
                  const uint2* __restrict__ w2p,
                  const uint2* __restrict__ w3c,
                  float* __restrict__ out)
{
    __shared__ uint2 s_h1[2][4][13][64];       // 53,248 B: fp8 h1 B-frags
    __shared__ float s_part[4][4][16][8];      // 8,192 B: [m][q][row][o]

    const int tid = threadIdx.x;
    const int wid = tid >> 6;
    const int ln  = tid & 63;
    const int g   = ln >> 4, c16 = ln & 15;
    const int brow = blockIdx.x << 8;

    long w2A[5][13];   // slice-wave resident W2p quarter (fp8 frags)
    long w3A[3];       // slice-wave resident W3 coeff frags

    if (wid < 4) {
        const int q = wid;
        const long* gw2 = (const long*)w2p;
        #pragma unroll
        for (int t = 0; t < 5; ++t)
            #pragma unroll
            for (int kt = 0; kt < 13; ++kt)
                w2A[t][kt] = gw2[((q * 5 + t) * 13 + kt) * 64 + ln];
        const long* gw3 = (const long*)w3c;
        #pragma unroll
        for (int k2 = 0; k2 < 3; ++k2)
            w3A[k2] = gw3[(q * 3 + k2) * 64 + ln];
    }

    // ---- phase A producer (waves 4-7): a = wid-4, kt set {a, a+4, a+8, (12 if a==0)}
    auto run_a = [&](int r, int buf) {
        const int a = wid - 4;
        const int cnt = (a == 0) ? 4 : 3;
        #pragma unroll 1
        for (int m = 0; m < 4; ++m) {
            const float* sp = state + (brow + r * 64 + m * 16 + c16) * 17;
            bf16x8 sb;
            if (g == 0) {
                #pragma unroll
                for (int j = 0; j < 8; ++j) sb[j] = (__bf16)sp[j];
            } else if (g == 1) {
                #pragma unroll
                for (int j = 0; j < 8; ++j) sb[j] = (__bf16)sp[8 + j];
            } else if (g == 2) {
                sb[0] = (__bf16)sp[16];
                sb[1] = (__bf16)1.0f;      // bias carrier k=17
                #pragma unroll
                for (int j = 2; j < 8; ++j) sb[j] = (__bf16)0.f;
            } else {
                #pragma unroll
                for (int j = 0; j < 8; ++j) sb[j] = (__bf16)0.f;
            }
            #pragma unroll
            for (int i = 0; i < 4; ++i) {
                if (i >= cnt) break;
                int kt = a + 4 * i;
                bf16x8 we = *(const bf16x8*)(w1p + ((2 * kt) * 64 + ln) * 8);
                bf16x8 wo = *(const bf16x8*)(w1p + ((2 * kt + 1) * 64 + ln) * 8);
                f32x4 ae = {0.f, 0.f, 0.f, 0.f}, ao = {0.f, 0.f, 0.f, 0.f};
                ae = __builtin_amdgcn_mfma_f32_16x16x32_bf16(we, sb, ae, 0, 0, 0);
                ao = __builtin_amdgcn_mfma_f32_16x16x32_bf16(wo, sb, ao, 0, 0, 0);
                uint2 d;
                d.x = pk8(lrelu(ae[0]), lrelu(ae[1])) | (pk8(lrelu(ae[2]), lrelu(ae[3])) << 16);
                d.y = pk8(lrelu(ao[0]), lrelu(ao[1])) | (pk8(lrelu(ao[2]), lrelu(ao[3])) << 16);
                s_h1[buf][m][kt][ln] = d;
            }
        }
    };

    if (wid >= 4) run_a(0, 0);
    __syncthreads();

    #pragma unroll 1
    for (int r = 0; r < 4; ++r) {
        const int buf = r & 1;
        if (wid < 4) {
            const int q = wid;
            #pragma unroll 1
            for (int m = 0; m < 4; ++m) {
                long fr[13];
                #pragma unroll
                for (int kt = 0; kt < 13; ++kt)
                    fr[kt] = *(const long*)(&s_h1[buf][m][kt][ln]);
                f32x4 acc[5];
                #pragma unroll
                for (int t = 0; t < 5; ++t) acc[t] = (f32x4){0.f, 0.f, 0.f, 0.f};
                #pragma unroll
                for (int kt = 0; kt < 13; ++kt)
                    #pragma unroll
                    for (int t = 0; t < 5; ++t)
                        acc[t] = __builtin_amdgcn_mfma_f32_16x16x32_fp8_fp8(
                                     w2A[t][kt], fr[kt], acc[t], 0, 0, 0);
                // z = lrelu(h2), packed fp8 per sigma2
                unsigned dw[5];
                #pragma unroll
                for (int t = 0; t < 5; ++t)
                    dw[t] = pk8(lrelu(acc[t][0]), lrelu(acc[t][1])) |
                            (pk8(lrelu(acc[t][2]), lrelu(acc[t][3])) << 16);
                long z0 = mk64(dw[0], dw[1]);
                long z1 = mk64(dw[2], dw[3]);
                long z2 = mk64(dw[4], 0u);
                f32x4 cc = {0.f, 0.f, 0.f, 0.f};
                cc = __builtin_amdgcn_mfma_f32_16x16x32_fp8_fp8(w3A[0], z0, cc, 0, 0, 0);
                cc = __builtin_amdgcn_mfma_f32_16x16x32_fp8_fp8(w3A[1], z1, cc, 0, 0, 0);
                cc = __builtin_amdgcn_mfma_f32_16x16x32_fp8_fp8(w3A[2], z2, cc, 0, 0, 0);
                if (g == 0) *(f32x4*)(&s_part[m][q][c16][0]) = cc;
                else if (g == 1) s_part[m][q][c16][4] = cc[0];   // o=4
            }
        } else if (r < 3) {
            run_a(r + 1, buf ^ 1);
        }
        __syncthreads();

        // ---- epilogue: waves 0-3, 16 lanes each -> 64 rows of this round ----
        if (wid < 4 && ln < 16) {
            const int m = wid;
            f32x4 sv = {0.f, 0.f, 0.f, 0.f};
            float s4 = 0.f;
            #pragma unroll
            for (int q = 0; q < 4; ++q) {
                sv += *(const f32x4*)(&s_part[m][q][ln][0]);
                s4 += s_part[m][q][ln][4];
            }
            float v[5];
            v[0] = -lrelu(sv[0]); v[1] = -lrelu(sv[1]);
            v[2] = -lrelu(sv[2]); v[3] = -lrelu(sv[3]);
            v[4] = -lrelu(s4);

            // exact QP: sum(clip(v - nu, 0, UB)) = SUM via breakpoints
            float bp[10];
            #pragma unroll
            for (int i = 0; i < 5; ++i) { bp[i] = v[i]; bp[i + 5] = v[i] - UBV; }
            float blo = -1e30f, glo = 0.f;
            #pragma unroll
            for (int j = 0; j < 10; ++j) {
                float b = bp[j];
                float gsum = 0.f;
                #pragma unroll
                for (int i = 0; i < 5; ++i) {
                    float zc = v[i] - b;
                    zc = fminf(fmaxf(zc, 0.f), UBV);
                    gsum += zc;
                }
                if (gsum >= SUMC && b > blo) { blo = b; glo = gsum; }
            }
            float bhi = 1e30f;
            #pragma unroll
            for (int j = 0; j < 10; ++j) {
                float b = bp[j];
                if (b > blo && b < bhi) bhi = b;
            }
            float mid = 0.5f * (blo + bhi);
            int nfree = 0;
            #pragma unroll
            for (int i = 0; i < 5; ++i)
                nfree += (v[i] > mid && v[i] < mid + UBV) ? 1 : 0;
            float nu = (nfree > 0) ? blo + (glo - SUMC) / (float)nfree : blo;

            int row = brow + r * 64 + m * 16 + ln;
            #pragma unroll
            for (int o = 0; o < 5; ++o) {
                float zf = v[o] - nu;
                zf = fminf(fmaxf(zf, 0.f), UBV);
                out[row * 5 + o] = zf;
            }
        }
        __syncthreads();
    }
}

extern "C" void kernel_launch(void* const* d_in, const int* in_sizes, int n_in,
                              void* d_out, int out_size, void* d_ws, size_t ws_size,
                              hipStream_t stream) {
    const float* state = (const float*)d_in[0];
    const float* W1    = (const float*)d_in[1];
    const float* b1    = (const float*)d_in[2];
    const float* W2    = (const float*)d_in[3];
    const float* b2    = (const float*)d_in[4];
    const float* W3    = (const float*)d_in[5];
    const float* b3    = (const float*)d_in[6];
    float* out = (float*)d_out;

    char* base = (char*)d_ws;
    __bf16* w1p = (__bf16*)base;                   // 1664 frags-lanes * 16B = 26,624B
    uint2*  w2p = (uint2*)(base + 26624);          // 16640 * 8B = 133,120B
    uint2*  w3c = (uint2*)(base + 26624 + 133120); // 768 * 8B   =   6,144B

    const int total = 1664 + 16640 + 768;          // 19,072 prep threads
    prep_kernel<<<(total + 255) / 256, 256, 0, stream>>>(W1, b1, W2, b2, W3, b3,
                                                         w1p, w2p, w3c);

    int B = in_sizes[0] / 17;                      // 65536
    actor_kernel<<<B / 256, 512, 0, stream>>>(state, w1p, w2p, w3c, out);
}

// Round 5
// 34.646 us; speedup vs baseline: 2.3842x; 1.0392x over previous
//
#include <hip/hip_runtime.h>
#include <hip/hip_bf16.h>

typedef __bf16 bf16x8 __attribute__((ext_vector_type(8)));
typedef float  f32x4  __attribute__((ext_vector_type(4)));

#define UBV   35.0f
#define SUMC  150.0f

__device__ __forceinline__ float lrelu(float x) { return fmaxf(x, 0.2f * x); }

// pack 2 f32 -> 2 fp8(e4m3) in low 16 bits
__device__ __forceinline__ unsigned pk8(float a, float b) {
    return ((unsigned)__builtin_amdgcn_cvt_pk_fp8_f32(a, b, 0, false)) & 0xffffu;
}
__device__ __forceinline__ long mk64(unsigned lo, unsigned hi) {
    return (long)(((unsigned long long)hi << 32) | (unsigned long long)lo);
}
__device__ __forceinline__ void async16(void* lds_uniform, const void* gsrc) {
    __builtin_amdgcn_global_load_lds(
        (__attribute__((address_space(1))) void*)(gsrc),
        (__attribute__((address_space(3))) void*)(lds_uniform),
        16, 0, 0);
}

// ---------------------------------------------------------------------------
// sigma mapping (phase A -> phase B handoff):
//   h1 k-slot kappa = kt*32 + g*8 + 4h + r   <->  acc tile nt=2kt+h, row rho=g*4+r
// W1p tile nt, row rho holds weights of slot kappa; the phase-A accumulator
// pair (2kt,2kt+1) packs directly into the phase-B B-frag for kt. Same trick
// for phase B -> C with kappa2 over each wave's 80 n2-slots (K=96 padded).
// Biases: state k=17 := 1.0 carries b1; h1 slot 400 := 1.0 carries b2;
// z local-slot 79 (==1.0 via b2col) carries b3/4 per quarter.
// (Verified numerically in R4: absmax 0.125.)
// ---------------------------------------------------------------------------

__global__ void prep_kernel(const float* __restrict__ W1, const float* __restrict__ b1,
                            const float* __restrict__ W2, const float* __restrict__ b2,
                            const float* __restrict__ W3, const float* __restrict__ b3,
                            __bf16* __restrict__ w1p, uint2* __restrict__ w2p,
                            uint2* __restrict__ w3c)
{
    int idx = blockIdx.x * blockDim.x + threadIdx.x;
    if (idx < 1664) {
        int lane = idx & 63;
        int nt = idx >> 6;
        int c16 = lane & 15, g = lane >> 4;
        int kk = nt >> 1, hh = nt & 1;
        int kap = kk * 32 + (c16 >> 2) * 8 + hh * 4 + (c16 & 3);
        bf16x8 v;
        #pragma unroll
        for (int j = 0; j < 8; ++j) {
            int k = g * 8 + j;
            float x = 0.f;
            if (kap < 400) {
                if (k < 17) x = W1[kap * 17 + k];
                else if (k == 17) x = b1[kap];
            } else if (kap == 400) {
                if (k == 17) x = 1.0f;
            }
            v[j] = (__bf16)x;
        }
        *(bf16x8*)(w1p + idx * 8) = v;
    } else if (idx < 1664 + 16640) {
        int i2 = idx - 1664;
        int fg = i2 >> 6, lane = i2 & 63;
        int q = fg / 65, rem = fg % 65;
        int t = rem / 13, kt = rem % 13;
        int c16 = lane & 15, g = lane >> 4;
        int local = t * 16 + c16;
        int ff = q * 79 + local;
        float v[8];
        #pragma unroll
        for (int j = 0; j < 8; ++j) {
            int kap = kt * 32 + g * 8 + j;
            float x = 0.f;
            if (local == 79) {
                x = (kap == 400) ? 1.0f : 0.f;
            } else if (local < 79 && ff < 300) {
                if (kap < 400) x = W2[ff * 400 + kap];
                else if (kap == 400) x = b2[ff];
            }
            v[j] = x;
        }
        uint2 d;
        d.x = pk8(v[0], v[1]) | (pk8(v[2], v[3]) << 16);
        d.y = pk8(v[4], v[5]) | (pk8(v[6], v[7]) << 16);
        w2p[i2] = d;
    } else if (idx < 1664 + 16640 + 768) {
        int i3 = idx - 1664 - 16640;
        int fg = i3 >> 6, lane = i3 & 63;
        int q = fg / 3, k2 = fg % 3;
        int o = lane & 15, g = lane >> 4;
        float v[8];
        #pragma unroll
        for (int j = 0; j < 8; ++j) {
            int t2  = 2 * k2 + (j >> 2);
            int rho = g * 4 + (j & 3);
            int local = t2 * 16 + rho;
            float x = 0.f;
            if (o < 5 && t2 < 5) {
                if (local == 79) x = b3[o] * 0.25f;
                else if (local < 79 && q * 79 + local < 300)
                    x = W3[o * 300 + q * 79 + local];
            }
            v[j] = x;
        }
        uint2 d;
        d.x = pk8(v[0], v[1]) | (pk8(v[2], v[3]) << 16);
        d.y = pk8(v[4], v[5]) | (pk8(v[6], v[7]) << 16);
        w3c[i3] = d;
    }
}

// ---------------------------------------------------------------------------
// Actor: 512 blocks x 512 threads (8 waves), block = 128 rows = 8 m-tiles.
// Wave w: quarter q = w&3 resident in fp8 VGPRs. Produces h1 for m-tile w
// (keeps own frags in regs + LDS copy), consumes own tile pre-barrier, then
// 3 sibling tiles post-barrier. 3 barriers total; all waves MFMA-active.
// ---------------------------------------------------------------------------
__global__ __launch_bounds__(512, 2)
void actor_kernel(const float* __restrict__ state,
                  const __bf16* __restrict__ w1p,
                  const uint2* __restrict__ w2p,
                  const uint2* __restrict__ w3c,
                  float* __restrict__ out)
{
    __shared__ __align__(16) __bf16 s_w1[1664 * 8];   // 26,624B W1p mirror
    __shared__ uint2 s_h1[8][13][64];                 // 53,248B fp8 h1 B-frags
    __shared__ float s_part[8][4][16][8];             // 16,384B [m][q][row][o]

    const int tid = threadIdx.x;
    const int wid = tid >> 6;
    const int ln  = tid & 63;
    const int g   = ln >> 4, c16 = ln & 15;
    const int q   = wid & 3;
    const int brow = blockIdx.x << 7;     // 128 rows/block

    // ---- stage W1p -> LDS (wave-uniform dest base; 1KB per wave per chunk) ----
    {
        char* lb = (char*)s_w1;
        const char* gb = (const char*)w1p;
        #pragma unroll
        for (int it = 0; it < 3; ++it)
            async16(lb + it * 8192 + wid * 1024, gb + it * 8192 + wid * 1024 + ln * 16);
        if (wid < 2)
            async16(lb + 24576 + wid * 1024, gb + 24576 + wid * 1024 + ln * 16);
    }

    // ---- resident W2 quarter + W3 coeffs (L2-hot, coalesced) ----
    long w2A[5][13];
    long w3A[3];
    {
        const long* gw2 = (const long*)w2p;
        #pragma unroll
        for (int t = 0; t < 5; ++t)
            #pragma unroll
            for (int kt = 0; kt < 13; ++kt)
                w2A[t][kt] = gw2[((q * 5 + t) * 13 + kt) * 64 + ln];
        const long* gw3 = (const long*)w3c;
        #pragma unroll
        for (int k2 = 0; k2 < 3; ++k2)
            w3A[k2] = gw3[(q * 3 + k2) * 64 + ln];
    }

    __syncthreads();   // W1 staged (compiler drains vmcnt before barrier)

    // ---- consume(m): 65+3 fp8 MFMA with resident quarter, partials -> LDS ----
    auto consume = [&](const long* fr, int m) {
        f32x4 acc[5];
        #pragma unroll
        for (int t = 0; t < 5; ++t) acc[t] = (f32x4){0.f, 0.f, 0.f, 0.f};
        #pragma unroll
        for (int kt = 0; kt < 13; ++kt)
            #pragma unroll
            for (int t = 0; t < 5; ++t)
                acc[t] = __builtin_amdgcn_mfma_f32_16x16x32_fp8_fp8(
                             w2A[t][kt], fr[kt], acc[t], 0, 0, 0);
        unsigned dw[5];
        #pragma unroll
        for (int t = 0; t < 5; ++t)
            dw[t] = pk8(lrelu(acc[t][0]), lrelu(acc[t][1])) |
                    (pk8(lrelu(acc[t][2]), lrelu(acc[t][3])) << 16);
        f32x4 cc = {0.f, 0.f, 0.f, 0.f};
        cc = __builtin_amdgcn_mfma_f32_16x16x32_fp8_fp8(w3A[0], mk64(dw[0], dw[1]), cc, 0, 0, 0);
        cc = __builtin_amdgcn_mfma_f32_16x16x32_fp8_fp8(w3A[1], mk64(dw[2], dw[3]), cc, 0, 0, 0);
        cc = __builtin_amdgcn_mfma_f32_16x16x32_fp8_fp8(w3A[2], mk64(dw[4], 0u),    cc, 0, 0, 0);
        if (g == 0)      *(f32x4*)(&s_part[m][q][c16][0]) = cc;
        else if (g == 1) s_part[m][q][c16][4] = cc[0];   // o=4
    };

    // ---- Phase A: produce h1 for m-tile = wid (own frags stay in regs) ----
    long fr[13];
    {
        const float* sp = state + (brow + wid * 16 + c16) * 17;
        bf16x8 sb;
        if (g == 0) {
            #pragma unroll
            for (int j = 0; j < 8; ++j) sb[j] = (__bf16)sp[j];
        } else if (g == 1) {
            #pragma unroll
            for (int j = 0; j < 8; ++j) sb[j] = (__bf16)sp[8 + j];
        } else if (g == 2) {
            sb[0] = (__bf16)sp[16];
            sb[1] = (__bf16)1.0f;          // bias carrier k=17
            #pragma unroll
            for (int j = 2; j < 8; ++j) sb[j] = (__bf16)0.f;
        } else {
            #pragma unroll
            for (int j = 0; j < 8; ++j) sb[j] = (__bf16)0.f;
        }
        #pragma unroll
        for (int kt = 0; kt < 13; ++kt) {
            bf16x8 we = *(const bf16x8*)(s_w1 + ((2 * kt) * 64 + ln) * 8);
            bf16x8 wo = *(const bf16x8*)(s_w1 + ((2 * kt + 1) * 64 + ln) * 8);
            f32x4 ae = {0.f, 0.f, 0.f, 0.f}, ao = {0.f, 0.f, 0.f, 0.f};
            ae = __builtin_amdgcn_mfma_f32_16x16x32_bf16(we, sb, ae, 0, 0, 0);
            ao = __builtin_amdgcn_mfma_f32_16x16x32_bf16(wo, sb, ao, 0, 0, 0);
            uint2 d;
            d.x = pk8(lrelu(ae[0]), lrelu(ae[1])) | (pk8(lrelu(ae[2]), lrelu(ae[3])) << 16);
            d.y = pk8(lrelu(ao[0]), lrelu(ao[1])) | (pk8(lrelu(ao[2]), lrelu(ao[3])) << 16);
            s_h1[wid][kt][ln] = d;
            fr[kt] = mk64(d.x, d.y);
        }
    }

    // ---- Phase B/C for own tile: pure-register path, pre-barrier ----
    consume(fr, wid);

    __syncthreads();   // all h1 tiles visible

    // ---- sibling tiles: (m,q) rotation covers each pair exactly once ----
    #pragma unroll 1
    for (int s = 1; s < 4; ++s) {
        const int m = (wid & 4) + ((wid + s) & 3);
        long fr2[13];
        #pragma unroll
        for (int kt = 0; kt < 13; ++kt)
            fr2[kt] = *(const long*)(&s_h1[m][kt][ln]);
        consume(fr2, m);
    }

    __syncthreads();   // all partials visible

    // ---- Epilogue: wave wid -> its m-tile's 16 rows; exact QP ----
    if (ln < 16) {
        f32x4 sv = {0.f, 0.f, 0.f, 0.f};
        float s4 = 0.f;
        #pragma unroll
        for (int qq = 0; qq < 4; ++qq) {
            sv += *(const f32x4*)(&s_part[wid][qq][ln][0]);
            s4 += s_part[wid][qq][ln][4];
        }
        float v[5];
        v[0] = -lrelu(sv[0]); v[1] = -lrelu(sv[1]);
        v[2] = -lrelu(sv[2]); v[3] = -lrelu(sv[3]);
        v[4] = -lrelu(s4);

        float bp[10];
        #pragma unroll
        for (int i = 0; i < 5; ++i) { bp[i] = v[i]; bp[i + 5] = v[i] - UBV; }
        float blo = -1e30f, glo = 0.f;
        #pragma unroll
        for (int j = 0; j < 10; ++j) {
            float b = bp[j];
            float gsum = 0.f;
            #pragma unroll
            for (int i = 0; i < 5; ++i) {
                float zc = v[i] - b;
                zc = fminf(fmaxf(zc, 0.f), UBV);
                gsum += zc;
            }
            if (gsum >= SUMC && b > blo) { blo = b; glo = gsum; }
        }
        float bhi = 1e30f;
        #pragma unroll
        for (int j = 0; j < 10; ++j) {
            float b = bp[j];
            if (b > blo && b < bhi) bhi = b;
        }
        float mid = 0.5f * (blo + bhi);
        int nfree = 0;
        #pragma unroll
        for (int i = 0; i < 5; ++i)
            nfree += (v[i] > mid && v[i] < mid + UBV) ? 1 : 0;
        float nu = (nfree > 0) ? blo + (glo - SUMC) / (float)nfree : blo;

        int row = brow + wid * 16 + ln;
        #pragma unroll
        for (int o = 0; o < 5; ++o) {
            float zf = v[o] - nu;
            zf = fminf(fmaxf(zf, 0.f), UBV);
            out[row * 5 + o] = zf;
        }
    }
}

extern "C" void kernel_launch(void* const* d_in, const int* in_sizes, int n_in,
                              void* d_out, int out_size, void* d_ws, size_t ws_size,
                              hipStream_t stream) {
    const float* state = (const float*)d_in[0];
    const float* W1    = (const float*)d_in[1];
    const float* b1    = (const float*)d_in[2];
    const float* W2    = (const float*)d_in[3];
    const float* b2    = (const float*)d_in[4];
    const float* W3    = (const float*)d_in[5];
    const float* b3    = (const float*)d_in[6];
    float* out = (float*)d_out;

    char* base = (char*)d_ws;
    __bf16* w1p = (__bf16*)base;                   // 26,624B
    uint2*  w2p = (uint2*)(base + 26624);          // 133,120B
    uint2*  w3c = (uint2*)(base + 26624 + 133120); // 6,144B

    const int total = 1664 + 16640 + 768;
    prep_kernel<<<(total + 255) / 256, 256, 0, stream>>>(W1, b1, W2, b2, W3, b3,
                                                         w1p, w2p, w3c);

    int B = in_sizes[0] / 17;                      // 65536
    actor_kernel<<<B / 128, 512, 0, stream>>>(state, w1p, w2p, w3c, out);
}

// Round 6
// 33.240 us; speedup vs baseline: 2.4850x; 1.0423x over previous
//
#include <hip/hip_runtime.h>
#include <hip/hip_bf16.h>

typedef __bf16 bf16x8 __attribute__((ext_vector_type(8)));
typedef float  f32x4  __attribute__((ext_vector_type(4)));

#define UBV   35.0f
#define SUMC  150.0f

__device__ __forceinline__ float lrelu(float x) { return fmaxf(x, 0.2f * x); }

// pack 2 f32 -> 2 fp8(e4m3) in low 16 bits
__device__ __forceinline__ unsigned pk8(float a, float b) {
    return ((unsigned)__builtin_amdgcn_cvt_pk_fp8_f32(a, b, 0, false)) & 0xffffu;
}
__device__ __forceinline__ long mk64(unsigned lo, unsigned hi) {
    return (long)(((unsigned long long)hi << 32) | (unsigned long long)lo);
}
__device__ __forceinline__ void async16(void* lds_uniform, const void* gsrc) {
    __builtin_amdgcn_global_load_lds(
        (__attribute__((address_space(1))) void*)(gsrc),
        (__attribute__((address_space(3))) void*)(lds_uniform),
        16, 0, 0);
}

// ---------------------------------------------------------------------------
// sigma mapping (phase A -> phase B handoff):
//   h1 k-slot kappa = kt*32 + g*8 + 4h + r   <->  acc tile nt=2kt+h, row rho=g*4+r
// W1p tile nt, row rho holds weights of slot kappa; the phase-A accumulator
// pair (2kt,2kt+1) packs directly into the phase-B B-frag for kt. Same trick
// for phase B -> C with kappa2 over each wave's 80 n2-slots (K=96 padded).
// Biases: state k=17 := 1.0 carries b1; h1 slot 400 := 1.0 carries b2;
// z local-slot 79 (==1.0 via b2col) carries b3/4 per quarter.
// (Verified numerically since R4: absmax 0.125.)
// ---------------------------------------------------------------------------

__global__ void prep_kernel(const float* __restrict__ W1, const float* __restrict__ b1,
                            const float* __restrict__ W2, const float* __restrict__ b2,
                            const float* __restrict__ W3, const float* __restrict__ b3,
                            __bf16* __restrict__ w1p, uint2* __restrict__ w2p,
                            uint2* __restrict__ w3c)
{
    int idx = blockIdx.x * blockDim.x + threadIdx.x;
    if (idx < 1664) {
        int lane = idx & 63;
        int nt = idx >> 6;
        int c16 = lane & 15, g = lane >> 4;
        int kk = nt >> 1, hh = nt & 1;
        int kap = kk * 32 + (c16 >> 2) * 8 + hh * 4 + (c16 & 3);
        bf16x8 v;
        #pragma unroll
        for (int j = 0; j < 8; ++j) {
            int k = g * 8 + j;
            float x = 0.f;
            if (kap < 400) {
                if (k < 17) x = W1[kap * 17 + k];
                else if (k == 17) x = b1[kap];
            } else if (kap == 400) {
                if (k == 17) x = 1.0f;
            }
            v[j] = (__bf16)x;
        }
        *(bf16x8*)(w1p + idx * 8) = v;
    } else if (idx < 1664 + 16640) {
        int i2 = idx - 1664;
        int fg = i2 >> 6, lane = i2 & 63;
        int q = fg / 65, rem = fg % 65;
        int t = rem / 13, kt = rem % 13;
        int c16 = lane & 15, g = lane >> 4;
        int local = t * 16 + c16;
        int ff = q * 79 + local;
        float v[8];
        #pragma unroll
        for (int j = 0; j < 8; ++j) {
            int kap = kt * 32 + g * 8 + j;
            float x = 0.f;
            if (local == 79) {
                x = (kap == 400) ? 1.0f : 0.f;
            } else if (local < 79 && ff < 300) {
                if (kap < 400) x = W2[ff * 400 + kap];
                else if (kap == 400) x = b2[ff];
            }
            v[j] = x;
        }
        uint2 d;
        d.x = pk8(v[0], v[1]) | (pk8(v[2], v[3]) << 16);
        d.y = pk8(v[4], v[5]) | (pk8(v[6], v[7]) << 16);
        w2p[i2] = d;
    } else if (idx < 1664 + 16640 + 768) {
        int i3 = idx - 1664 - 16640;
        int fg = i3 >> 6, lane = i3 & 63;
        int q = fg / 3, k2 = fg % 3;
        int o = lane & 15, g = lane >> 4;
        float v[8];
        #pragma unroll
        for (int j = 0; j < 8; ++j) {
            int t2  = 2 * k2 + (j >> 2);
            int rho = g * 4 + (j & 3);
            int local = t2 * 16 + rho;
            float x = 0.f;
            if (o < 5 && t2 < 5) {
                if (local == 79) x = b3[o] * 0.25f;
                else if (local < 79 && q * 79 + local < 300)
                    x = W3[o * 300 + q * 79 + local];
            }
            v[j] = x;
        }
        uint2 d;
        d.x = pk8(v[0], v[1]) | (pk8(v[2], v[3]) << 16);
        d.y = pk8(v[4], v[5]) | (pk8(v[6], v[7]) << 16);
        w3c[i3] = d;
    }
}

// ---------------------------------------------------------------------------
// Actor: 256 blocks x 512 threads (8 waves) = 1 block/CU, 8 waves/CU,
// full 256-VGPR budget (launch_bounds(512,1) -- R5's (512,2) forced <=128
// VGPR and spilled the 130-reg resident W2 quarter to scratch).
// Block = 256 rows = 2 groups x 8 m-tiles. Wave w: quarter q = w&3 resident
// in fp8 VGPRs; per group it produces h1 for m-tile w (frags stay in regs +
// LDS copy), consumes own tile pre-barrier, then 3 sibling tiles. s_part is
// ping-ponged so each group needs only 2 barriers (5 total).
// ---------------------------------------------------------------------------
__global__ __launch_bounds__(512, 1)
void actor_kernel(const float* __restrict__ state,
                  const __bf16* __restrict__ w1p,
                  const uint2* __restrict__ w2p,
                  const uint2* __restrict__ w3c,
                  float* __restrict__ out)
{
    __shared__ __align__(16) __bf16 s_w1[1664 * 8];   // 26,624B W1p mirror
    __shared__ uint2 s_h1[8][13][64];                 // 53,248B fp8 h1 B-frags
    __shared__ float s_part[2][8][4][16][8];          // 32,768B [pb][m][q][row][o]

    const int tid = threadIdx.x;
    const int wid = tid >> 6;
    const int ln  = tid & 63;
    const int g   = ln >> 4, c16 = ln & 15;
    const int q   = wid & 3;
    const int brow = blockIdx.x << 8;     // 256 rows/block

    // ---- stage W1p -> LDS (wave-uniform dest base; 1KB per wave per chunk) ----
    {
        char* lb = (char*)s_w1;
        const char* gb = (const char*)w1p;
        #pragma unroll
        for (int it = 0; it < 3; ++it)
            async16(lb + it * 8192 + wid * 1024, gb + it * 8192 + wid * 1024 + ln * 16);
        if (wid < 2)
            async16(lb + 24576 + wid * 1024, gb + 24576 + wid * 1024 + ln * 16);
    }

    // ---- resident W2 quarter + W3 coeffs (L2-hot, coalesced; 136 VGPR) ----
    long w2A[5][13];
    long w3A[3];
    {
        const long* gw2 = (const long*)w2p;
        #pragma unroll
        for (int t = 0; t < 5; ++t)
            #pragma unroll
            for (int kt = 0; kt < 13; ++kt)
                w2A[t][kt] = gw2[((q * 5 + t) * 13 + kt) * 64 + ln];
        const long* gw3 = (const long*)w3c;
        #pragma unroll
        for (int k2 = 0; k2 < 3; ++k2)
            w3A[k2] = gw3[(q * 3 + k2) * 64 + ln];
    }

    __syncthreads();   // W1 staged (compiler drains vmcnt before barrier)

    // ---- consume(m): 65+3 fp8 MFMA with resident quarter, partials -> LDS ----
    auto consume = [&](const long* fr, int m, int pb) {
        f32x4 acc[5];
        #pragma unroll
        for (int t = 0; t < 5; ++t) acc[t] = (f32x4){0.f, 0.f, 0.f, 0.f};
        #pragma unroll
        for (int kt = 0; kt < 13; ++kt)
            #pragma unroll
            for (int t = 0; t < 5; ++t)
                acc[t] = __builtin_amdgcn_mfma_f32_16x16x32_fp8_fp8(
                             w2A[t][kt], fr[kt], acc[t], 0, 0, 0);
        unsigned dw[5];
        #pragma unroll
        for (int t = 0; t < 5; ++t)
            dw[t] = pk8(lrelu(acc[t][0]), lrelu(acc[t][1])) |
                    (pk8(lrelu(acc[t][2]), lrelu(acc[t][3])) << 16);
        f32x4 cc = {0.f, 0.f, 0.f, 0.f};
        cc = __builtin_amdgcn_mfma_f32_16x16x32_fp8_fp8(w3A[0], mk64(dw[0], dw[1]), cc, 0, 0, 0);
        cc = __builtin_amdgcn_mfma_f32_16x16x32_fp8_fp8(w3A[1], mk64(dw[2], dw[3]), cc, 0, 0, 0);
        cc = __builtin_amdgcn_mfma_f32_16x16x32_fp8_fp8(w3A[2], mk64(dw[4], 0u),    cc, 0, 0, 0);
        if (g == 0)      *(f32x4*)(&s_part[pb][m][q][c16][0]) = cc;
        else if (g == 1) s_part[pb][m][q][c16][4] = cc[0];   // o=4
    };

    #pragma unroll 1
    for (int grp = 0; grp < 2; ++grp) {
        const int pb = grp & 1;
        const int gbase = brow + grp * 128;

        // ---- Phase A: produce h1 for m-tile = wid (own frags stay in regs) ----
        long fr[13];
        {
            const float* sp = state + (gbase + wid * 16 + c16) * 17;
            bf16x8 sb;
            if (g == 0) {
                #pragma unroll
                for (int j = 0; j < 8; ++j) sb[j] = (__bf16)sp[j];
            } else if (g == 1) {
                #pragma unroll
                for (int j = 0; j < 8; ++j) sb[j] = (__bf16)sp[8 + j];
            } else if (g == 2) {
                sb[0] = (__bf16)sp[16];
                sb[1] = (__bf16)1.0f;          // bias carrier k=17
                #pragma unroll
                for (int j = 2; j < 8; ++j) sb[j] = (__bf16)0.f;
            } else {
                #pragma unroll
                for (int j = 0; j < 8; ++j) sb[j] = (__bf16)0.f;
            }
            #pragma unroll
            for (int kt = 0; kt < 13; ++kt) {
                bf16x8 we = *(const bf16x8*)(s_w1 + ((2 * kt) * 64 + ln) * 8);
                bf16x8 wo = *(const bf16x8*)(s_w1 + ((2 * kt + 1) * 64 + ln) * 8);
                f32x4 ae = {0.f, 0.f, 0.f, 0.f}, ao = {0.f, 0.f, 0.f, 0.f};
                ae = __builtin_amdgcn_mfma_f32_16x16x32_bf16(we, sb, ae, 0, 0, 0);
                ao = __builtin_amdgcn_mfma_f32_16x16x32_bf16(wo, sb, ao, 0, 0, 0);
                uint2 d;
                d.x = pk8(lrelu(ae[0]), lrelu(ae[1])) | (pk8(lrelu(ae[2]), lrelu(ae[3])) << 16);
                d.y = pk8(lrelu(ao[0]), lrelu(ao[1])) | (pk8(lrelu(ao[2]), lrelu(ao[3])) << 16);
                s_h1[wid][kt][ln] = d;
                fr[kt] = mk64(d.x, d.y);
            }
        }

        // ---- Phase B/C for own tile: pure-register path, pre-barrier ----
        consume(fr, wid, pb);

        __syncthreads();   // all h1 tiles of this group visible

        // ---- sibling tiles: (m,q) rotation covers each pair exactly once ----
        #pragma unroll 1
        for (int s = 1; s < 4; ++s) {
            const int m = (wid & 4) + ((wid + s) & 3);
            long fr2[13];
            #pragma unroll
            for (int kt = 0; kt < 13; ++kt)
                fr2[kt] = *(const long*)(&s_h1[m][kt][ln]);
            consume(fr2, m, pb);
        }

        __syncthreads();   // partials visible; s_h1 free for next group

        // ---- Epilogue: wave wid -> its m-tile's 16 rows; exact QP ----
        // (overlaps next group's phase A; s_part is ping-ponged)
        if (ln < 16) {
            f32x4 sv = {0.f, 0.f, 0.f, 0.f};
            float s4 = 0.f;
            #pragma unroll
            for (int qq = 0; qq < 4; ++qq) {
                sv += *(const f32x4*)(&s_part[pb][wid][qq][ln][0]);
                s4 += s_part[pb][wid][qq][ln][4];
            }
            float v[5];
            v[0] = -lrelu(sv[0]); v[1] = -lrelu(sv[1]);
            v[2] = -lrelu(sv[2]); v[3] = -lrelu(sv[3]);
            v[4] = -lrelu(s4);

            float bp[10];
            #pragma unroll
            for (int i = 0; i < 5; ++i) { bp[i] = v[i]; bp[i + 5] = v[i] - UBV; }
            float blo = -1e30f, glo = 0.f;
            #pragma unroll
            for (int j = 0; j < 10; ++j) {
                float b = bp[j];
                float gsum = 0.f;
                #pragma unroll
                for (int i = 0; i < 5; ++i) {
                    float zc = v[i] - b;
                    zc = fminf(fmaxf(zc, 0.f), UBV);
                    gsum += zc;
                }
                if (gsum >= SUMC && b > blo) { blo = b; glo = gsum; }
            }
            float bhi = 1e30f;
            #pragma unroll
            for (int j = 0; j < 10; ++j) {
                float b = bp[j];
                if (b > blo && b < bhi) bhi = b;
            }
            float mid = 0.5f * (blo + bhi);
            int nfree = 0;
            #pragma unroll
            for (int i = 0; i < 5; ++i)
                nfree += (v[i] > mid && v[i] < mid + UBV) ? 1 : 0;
            float nu = (nfree > 0) ? blo + (glo - SUMC) / (float)nfree : blo;

            int row = gbase + wid * 16 + ln;
            #pragma unroll
            for (int o = 0; o < 5; ++o) {
                float zf = v[o] - nu;
                zf = fminf(fmaxf(zf, 0.f), UBV);
                out[row * 5 + o] = zf;
            }
        }
    }
}

extern "C" void kernel_launch(void* const* d_in, const int* in_sizes, int n_in,
                              void* d_out, int out_size, void* d_ws, size_t ws_size,
                              hipStream_t stream) {
    const float* state = (const float*)d_in[0];
    const float* W1    = (const float*)d_in[1];
    const float* b1    = (const float*)d_in[2];
    const float* W2    = (const float*)d_in[3];
    const float* b2    = (const float*)d_in[4];
    const float* W3    = (const float*)d_in[5];
    const float* b3    = (const float*)d_in[6];
    float* out = (float*)d_out;

    char* base = (char*)d_ws;
    __bf16* w1p = (__bf16*)base;                   // 26,624B
    uint2*  w2p = (uint2*)(base + 26624);          // 133,120B
    uint2*  w3c = (uint2*)(base + 26624 + 133120); // 6,144B

    const int total = 1664 + 16640 + 768;
    prep_kernel<<<(total + 255) / 256, 256, 0, stream>>>(W1, b1, W2, b2, W3, b3,
                                                         w1p, w2p, w3c);

    int B = in_sizes[0] / 17;                      // 65536
    actor_kernel<<<B / 256, 512, 0, stream>>>(state, w1p, w2p, w3c, out);
}

// Round 7
// 30.916 us; speedup vs baseline: 2.6718x; 1.0752x over previous
//
#include <hip/hip_runtime.h>
#include <hip/hip_bf16.h>

typedef __bf16 bf16x8 __attribute__((ext_vector_type(8)));
typedef float  f32x4  __attribute__((ext_vector_type(4)));

#define UBV   35.0f
#define SUMC  150.0f

__device__ __forceinline__ float lrelu(float x) { return fmaxf(x, 0.2f * x); }

// pack 2 f32 -> 2 fp8(e4m3) in low 16 bits
__device__ __forceinline__ unsigned pk8(float a, float b) {
    return ((unsigned)__builtin_amdgcn_cvt_pk_fp8_f32(a, b, 0, false)) & 0xffffu;
}
__device__ __forceinline__ long mk64(unsigned lo, unsigned hi) {
    return (long)(((unsigned long long)hi << 32) | (unsigned long long)lo);
}
__device__ __forceinline__ void async16(void* lds_uniform, const void* gsrc) {
    __builtin_amdgcn_global_load_lds(
        (__attribute__((address_space(1))) void*)(gsrc),
        (__attribute__((address_space(3))) void*)(lds_uniform),
        16, 0, 0);
}

// ---------------------------------------------------------------------------
// sigma mapping (phase A -> phase B handoff):
//   h1 k-slot kappa = kt*32 + g*8 + 4h + r   <->  acc tile nt=2kt+h, row rho=g*4+r
// W1p tile nt, row rho holds weights of slot kappa; the phase-A accumulator
// pair (2kt,2kt+1) packs directly into the phase-B B-frag for kt. Same trick
// for phase B -> C with kappa2 over each wave's 80 n2-slots (K=96 padded).
// Biases: state k=17 := 1.0 carries b1; h1 slot 400 := 1.0 carries b2;
// z local-slot 79 (==1.0 via b2col) carries b3/4 per quarter.
// (Verified numerically since R4: absmax 0.125.)
// ---------------------------------------------------------------------------

__global__ void prep_kernel(const float* __restrict__ W1, const float* __restrict__ b1,
                            const float* __restrict__ W2, const float* __restrict__ b2,
                            const float* __restrict__ W3, const float* __restrict__ b3,
                            __bf16* __restrict__ w1p, uint2* __restrict__ w2p,
                            uint2* __restrict__ w3c)
{
    int idx = blockIdx.x * blockDim.x + threadIdx.x;
    if (idx < 1664) {
        int lane = idx & 63;
        int nt = idx >> 6;
        int c16 = lane & 15, g = lane >> 4;
        int kk = nt >> 1, hh = nt & 1;
        int kap = kk * 32 + (c16 >> 2) * 8 + hh * 4 + (c16 & 3);
        bf16x8 v;
        #pragma unroll
        for (int j = 0; j < 8; ++j) {
            int k = g * 8 + j;
            float x = 0.f;
            if (kap < 400) {
                if (k < 17) x = W1[kap * 17 + k];
                else if (k == 17) x = b1[kap];
            } else if (kap == 400) {
                if (k == 17) x = 1.0f;
            }
            v[j] = (__bf16)x;
        }
        *(bf16x8*)(w1p + idx * 8) = v;
    } else if (idx < 1664 + 16640) {
        int i2 = idx - 1664;
        int fg = i2 >> 6, lane = i2 & 63;
        int q = fg / 65, rem = fg % 65;
        int t = rem / 13, kt = rem % 13;
        int c16 = lane & 15, g = lane >> 4;
        int local = t * 16 + c16;
        int ff = q * 79 + local;
        float v[8];
        #pragma unroll
        for (int j = 0; j < 8; ++j) {
            int kap = kt * 32 + g * 8 + j;
            float x = 0.f;
            if (local == 79) {
                x = (kap == 400) ? 1.0f : 0.f;
            } else if (local < 79 && ff < 300) {
                if (kap < 400) x = W2[ff * 400 + kap];
                else if (kap == 400) x = b2[ff];
            }
            v[j] = x;
        }
        uint2 d;
        d.x = pk8(v[0], v[1]) | (pk8(v[2], v[3]) << 16);
        d.y = pk8(v[4], v[5]) | (pk8(v[6], v[7]) << 16);
        w2p[i2] = d;
    } else if (idx < 1664 + 16640 + 768) {
        int i3 = idx - 1664 - 16640;
        int fg = i3 >> 6, lane = i3 & 63;
        int q = fg / 3, k2 = fg % 3;
        int o = lane & 15, g = lane >> 4;
        float v[8];
        #pragma unroll
        for (int j = 0; j < 8; ++j) {
            int t2  = 2 * k2 + (j >> 2);
            int rho = g * 4 + (j & 3);
            int local = t2 * 16 + rho;
            float x = 0.f;
            if (o < 5 && t2 < 5) {
                if (local == 79) x = b3[o] * 0.25f;
                else if (local < 79 && q * 79 + local < 300)
                    x = W3[o * 300 + q * 79 + local];
            }
            v[j] = x;
        }
        uint2 d;
        d.x = pk8(v[0], v[1]) | (pk8(v[2], v[3]) << 16);
        d.y = pk8(v[4], v[5]) | (pk8(v[6], v[7]) << 16);
        w3c[i3] = d;
    }
}

// ---------------------------------------------------------------------------
// Actor: 1024 blocks x 256 threads (4 waves), 64 rows/block -> 2 co-resident
// blocks/CU (VGPR ~248 caps at 8 waves/CU; LDS 60KB/block -> 120KB/CU).
// Independent blocks decouple barriers: while one block barriers/epilogues,
// the other's waves fill the SIMDs (R4-R6 were single-block-per-CU lockstep).
// Wave w: quarter q=w resident in fp8 VGPRs; produces h1 m-tile w (frags stay
// in regs + LDS copy), consumes own tile pre-barrier, then 3 siblings.
// ---------------------------------------------------------------------------
__global__ __launch_bounds__(256, 2)
void actor_kernel(const float* __restrict__ state,
                  const __bf16* __restrict__ w1p,
                  const uint2* __restrict__ w2p,
                  const uint2* __restrict__ w3c,
                  float* __restrict__ out)
{
    __shared__ __align__(16) __bf16 s_w1[1664 * 8];   // 26,624B W1p mirror
    __shared__ uint2 s_h1[4][13][64];                 // 26,624B fp8 h1 B-frags
    __shared__ float s_part[4][4][16][8];             //  8,192B [m][q][row][o]

    const int tid = threadIdx.x;
    const int wid = tid >> 6;            // wave = quarter = own m-tile
    const int ln  = tid & 63;
    const int g   = ln >> 4, c16 = ln & 15;
    const int brow = blockIdx.x << 6;    // 64 rows/block

    // ---- state loads FIRST (longest-latency consumer is phase A) ----
    const float* sp = state + (brow + wid * 16 + c16) * 17;
    float s0[8], s1[8];
    float s16;
    {
        #pragma unroll
        for (int j = 0; j < 8; ++j) s0[j] = sp[j];
        #pragma unroll
        for (int j = 0; j < 8; ++j) s1[j] = sp[8 + j];
        s16 = sp[16];
    }

    // ---- stage W1p -> LDS (26 chunks of 1KB; wave-uniform dest base) ----
    {
        char* lb = (char*)s_w1;
        const char* gb = (const char*)w1p;
        #pragma unroll
        for (int i = wid; i < 26; i += 4)
            async16(lb + i * 1024, gb + i * 1024 + ln * 16);
    }

    // ---- resident W2 quarter + W3 coeffs (L2-hot, coalesced; 136 VGPR) ----
    long w2A[5][13];
    long w3A[3];
    {
        const long* gw2 = (const long*)w2p;
        #pragma unroll
        for (int t = 0; t < 5; ++t)
            #pragma unroll
            for (int kt = 0; kt < 13; ++kt)
                w2A[t][kt] = gw2[((wid * 5 + t) * 13 + kt) * 64 + ln];
        const long* gw3 = (const long*)w3c;
        #pragma unroll
        for (int k2 = 0; k2 < 3; ++k2)
            w3A[k2] = gw3[(wid * 3 + k2) * 64 + ln];
    }

    __syncthreads();   // W1 staged (vmcnt drained by compiler before barrier)

    // ---- consume(m): 65+3 fp8 MFMA with resident quarter, partials -> LDS ----
    auto consume = [&](const long* fr, int m) {
        f32x4 acc[5];
        #pragma unroll
        for (int t = 0; t < 5; ++t) acc[t] = (f32x4){0.f, 0.f, 0.f, 0.f};
        #pragma unroll
        for (int kt = 0; kt < 13; ++kt)
            #pragma unroll
            for (int t = 0; t < 5; ++t)
                acc[t] = __builtin_amdgcn_mfma_f32_16x16x32_fp8_fp8(
                             w2A[t][kt], fr[kt], acc[t], 0, 0, 0);
        unsigned dw[5];
        #pragma unroll
        for (int t = 0; t < 5; ++t)
            dw[t] = pk8(lrelu(acc[t][0]), lrelu(acc[t][1])) |
                    (pk8(lrelu(acc[t][2]), lrelu(acc[t][3])) << 16);
        f32x4 cc = {0.f, 0.f, 0.f, 0.f};
        cc = __builtin_amdgcn_mfma_f32_16x16x32_fp8_fp8(w3A[0], mk64(dw[0], dw[1]), cc, 0, 0, 0);
        cc = __builtin_amdgcn_mfma_f32_16x16x32_fp8_fp8(w3A[1], mk64(dw[2], dw[3]), cc, 0, 0, 0);
        cc = __builtin_amdgcn_mfma_f32_16x16x32_fp8_fp8(w3A[2], mk64(dw[4], 0u),    cc, 0, 0, 0);
        if (g == 0)      *(f32x4*)(&s_part[m][wid][c16][0]) = cc;
        else if (g == 1) s_part[m][wid][c16][4] = cc[0];   // o=4
    };

    // ---- Phase A: produce h1 for m-tile = wid (own frags stay in regs) ----
    long fr[13];
    {
        bf16x8 sb;
        if (g == 0) {
            #pragma unroll
            for (int j = 0; j < 8; ++j) sb[j] = (__bf16)s0[j];
        } else if (g == 1) {
            #pragma unroll
            for (int j = 0; j < 8; ++j) sb[j] = (__bf16)s1[j];
        } else if (g == 2) {
            sb[0] = (__bf16)s16;
            sb[1] = (__bf16)1.0f;          // bias carrier k=17
            #pragma unroll
            for (int j = 2; j < 8; ++j) sb[j] = (__bf16)0.f;
        } else {
            #pragma unroll
            for (int j = 0; j < 8; ++j) sb[j] = (__bf16)0.f;
        }
        #pragma unroll
        for (int kt = 0; kt < 13; ++kt) {
            bf16x8 we = *(const bf16x8*)(s_w1 + ((2 * kt) * 64 + ln) * 8);
            bf16x8 wo = *(const bf16x8*)(s_w1 + ((2 * kt + 1) * 64 + ln) * 8);
            f32x4 ae = {0.f, 0.f, 0.f, 0.f}, ao = {0.f, 0.f, 0.f, 0.f};
            ae = __builtin_amdgcn_mfma_f32_16x16x32_bf16(we, sb, ae, 0, 0, 0);
            ao = __builtin_amdgcn_mfma_f32_16x16x32_bf16(wo, sb, ao, 0, 0, 0);
            uint2 d;
            d.x = pk8(lrelu(ae[0]), lrelu(ae[1])) | (pk8(lrelu(ae[2]), lrelu(ae[3])) << 16);
            d.y = pk8(lrelu(ao[0]), lrelu(ao[1])) | (pk8(lrelu(ao[2]), lrelu(ao[3])) << 16);
            s_h1[wid][kt][ln] = d;
            fr[kt] = mk64(d.x, d.y);
        }
    }

    // ---- Phase B/C for own tile: pure-register path, pre-barrier ----
    consume(fr, wid);

    __syncthreads();   // all 4 h1 tiles visible

    // ---- sibling tiles: rotation covers each (m, quarter) exactly once ----
    #pragma unroll 1
    for (int s = 1; s < 4; ++s) {
        const int m = (wid + s) & 3;
        long fr2[13];
        #pragma unroll
        for (int kt = 0; kt < 13; ++kt)
            fr2[kt] = *(const long*)(&s_h1[m][kt][ln]);
        consume(fr2, m);
    }

    __syncthreads();   // all partials visible

    // ---- Epilogue: wave wid -> its m-tile's 16 rows; exact QP ----
    if (ln < 16) {
        f32x4 sv = {0.f, 0.f, 0.f, 0.f};
        float s4 = 0.f;
        #pragma unroll
        for (int qq = 0; qq < 4; ++qq) {
            sv += *(const f32x4*)(&s_part[wid][qq][ln][0]);
            s4 += s_part[wid][qq][ln][4];
        }
        float v[5];
        v[0] = -lrelu(sv[0]); v[1] = -lrelu(sv[1]);
        v[2] = -lrelu(sv[2]); v[3] = -lrelu(sv[3]);
        v[4] = -lrelu(s4);

        float bp[10];
        #pragma unroll
        for (int i = 0; i < 5; ++i) { bp[i] = v[i]; bp[i + 5] = v[i] - UBV; }
        float blo = -1e30f, glo = 0.f;
        #pragma unroll
        for (int j = 0; j < 10; ++j) {
            float b = bp[j];
            float gsum = 0.f;
            #pragma unroll
            for (int i = 0; i < 5; ++i) {
                float zc = v[i] - b;
                zc = fminf(fmaxf(zc, 0.f), UBV);
                gsum += zc;
            }
            if (gsum >= SUMC && b > blo) { blo = b; glo = gsum; }
        }
        float bhi = 1e30f;
        #pragma unroll
        for (int j = 0; j < 10; ++j) {
            float b = bp[j];
            if (b > blo && b < bhi) bhi = b;
        }
        float mid = 0.5f * (blo + bhi);
        int nfree = 0;
        #pragma unroll
        for (int i = 0; i < 5; ++i)
            nfree += (v[i] > mid && v[i] < mid + UBV) ? 1 : 0;
        float nu = (nfree > 0) ? blo + (glo - SUMC) / (float)nfree : blo;

        int row = brow + wid * 16 + ln;
        #pragma unroll
        for (int o = 0; o < 5; ++o) {
            float zf = v[o] - nu;
            zf = fminf(fmaxf(zf, 0.f), UBV);
            out[row * 5 + o] = zf;
        }
    }
}

extern "C" void kernel_launch(void* const* d_in, const int* in_sizes, int n_in,
                              void* d_out, int out_size, void* d_ws, size_t ws_size,
                              hipStream_t stream) {
    const float* state = (const float*)d_in[0];
    const float* W1    = (const float*)d_in[1];
    const float* b1    = (const float*)d_in[2];
    const float* W2    = (const float*)d_in[3];
    const float* b2    = (const float*)d_in[4];
    const float* W3    = (const float*)d_in[5];
    const float* b3    = (const float*)d_in[6];
    float* out = (float*)d_out;

    char* base = (char*)d_ws;
    __bf16* w1p = (__bf16*)base;                   // 26,624B
    uint2*  w2p = (uint2*)(base + 26624);          // 133,120B
    uint2*  w3c = (uint2*)(base + 26624 + 133120); // 6,144B

    const int total = 1664 + 16640 + 768;
    prep_kernel<<<(total + 255) / 256, 256, 0, stream>>>(W1, b1, W2, b2, W3, b3,
                                                         w1p, w2p, w3c);

    int B = in_sizes[0] / 17;                      // 65536
    actor_kernel<<<B / 64, 256, 0, stream>>>(state, w1p, w2p, w3c, out);
}